// Round 1
// 343.254 us; speedup vs baseline: 1.0620x; 1.0620x over previous
//
#include <hip/hip_runtime.h>
#include <math.h>

#define BN   32
#define CN   256
#define HWN  4096   // 64*64
#define AUXN 64
#define RANKN 64
#define HIDN 256
#define OSN  8

// ---------------- workspace layout (floats) ----------------
#define WS_GPART 0        // [b][16][256] per-tile channel partial sums (131072)
#define WS_HT    131072   // h transposed [k][b] (8192)
#define WS_PHIC  139264   // (2048)
#define WS_MBC   141312   // (8192)
#define WS_SM    149504   // (256) unused now, kept for layout stability
#define WS_SIGC  149760   // (8192)
#define WS_Y     157952   // [b][2][4096] (262144)
#define WS_SIGS  420096   // [b][4096] (131072)

// K1: single pass over x with float4 loads.
//  - per-px channel mean/max (y): registers + tiny cross-wave LDS combine
//  - per-tile channel sums (gpart): stride-65 LDS (bank (c+l)%32: conflict-free)
__global__ __launch_bounds__(256) void k_stats(const float* __restrict__ x,
                                               float* __restrict__ gpart,
                                               float* __restrict__ y) {
  int b = blockIdx.y, tile = blockIdx.x, t = threadIdx.x;
  int w = t >> 6, l = t & 63;
  __shared__ float csum[256 * 65];           // 66.56 KB
  __shared__ float4 s_comb[4][64];           // 4 KB
  __shared__ float4 m_comb[4][64];           // 4 KB  -> 74.75 KB total, 2 blocks/CU
  const float4* xb4 = (const float4*)(x + (size_t)b * CN * HWN + tile * 256);
  float4 s4 = {0.f, 0.f, 0.f, 0.f};
  float4 m4 = {-INFINITY, -INFINITY, -INFINITY, -INFINITY};
  int c0 = w << 6;
#pragma unroll 8
  for (int cl = 0; cl < 64; cl++) {
    int c = c0 + cl;
    float4 v = xb4[(size_t)c * 1024 + l];
    s4.x += v.x; s4.y += v.y; s4.z += v.z; s4.w += v.w;
    m4.x = fmaxf(m4.x, v.x); m4.y = fmaxf(m4.y, v.y);
    m4.z = fmaxf(m4.z, v.z); m4.w = fmaxf(m4.w, v.w);
    csum[c * 65 + l] = (v.x + v.y) + (v.z + v.w);   // banks (c+l)%32: conflict-free
  }
  s_comb[w][l] = s4;
  m_comb[w][l] = m4;
  __syncthreads();
  // one thread per channel; volatile keeps scalar ds_read_b32 (2-way = free)
  {
    const volatile float* row = csum + t * 65;
    float g0 = 0.f, g1 = 0.f, g2 = 0.f, g3 = 0.f;
#pragma unroll
    for (int j = 0; j < 64; j += 4) {
      g0 += row[j]; g1 += row[j + 1]; g2 += row[j + 2]; g3 += row[j + 3];
    }
    gpart[(((size_t)b * 16 + tile) << 8) + t] = (g0 + g1) + (g2 + g3);
  }
  if (w == 0) {
    float4 a0 = s_comb[0][l], a1 = s_comb[1][l], a2 = s_comb[2][l], a3 = s_comb[3][l];
    float4 b0 = m_comb[0][l], b1 = m_comb[1][l], b2 = m_comb[2][l], b3 = m_comb[3][l];
    float4 sa, ma;
    sa.x = (a0.x + a1.x) + (a2.x + a3.x);
    sa.y = (a0.y + a1.y) + (a2.y + a3.y);
    sa.z = (a0.z + a1.z) + (a2.z + a3.z);
    sa.w = (a0.w + a1.w) + (a2.w + a3.w);
    ma.x = fmaxf(fmaxf(b0.x, b1.x), fmaxf(b2.x, b3.x));
    ma.y = fmaxf(fmaxf(b0.y, b1.y), fmaxf(b2.y, b3.y));
    ma.z = fmaxf(fmaxf(b0.z, b1.z), fmaxf(b2.z, b3.z));
    ma.w = fmaxf(fmaxf(b0.w, b1.w), fmaxf(b2.w, b3.w));
    const float inv = 1.0f / 256.0f;
    float4 avg = {sa.x * inv, sa.y * inv, sa.z * inv, sa.w * inv};
    ((float4*)(y + (size_t)b * 2 * HWN + tile * 256))[l] = avg;
    ((float4*)(y + ((size_t)b * 2 + 1) * HWN + tile * 256))[l] = ma;
  }
}

// K2: per-batch MLP head + the sigs stencil (y and sm both live here).
__global__ __launch_bounds__(256) void k_head(
    const float* __restrict__ gpart, const float* __restrict__ a,
    const float* __restrict__ W_pre, const float* __restrict__ b_pre,
    const float* __restrict__ W_bc,  const float* __restrict__ b_bc,
    const float* __restrict__ W_bs,  const float* __restrict__ b_bs,
    const float* __restrict__ W_pc,  const float* __restrict__ b_pc,
    const float* __restrict__ W_ps,  const float* __restrict__ b_ps,
    const float* __restrict__ W_Ws,  const float* __restrict__ b_Ws,
    const float* __restrict__ y,
    float* __restrict__ h_t_out, float* __restrict__ phic_out,
    float* __restrict__ mbc_out, float* __restrict__ sigs) {
  int b = blockIdx.x, t = threadIdx.x;
  __shared__ float in_s[320];
  __shared__ float h_s[256];
  __shared__ float phic_s[64], phis_s[64];
  __shared__ float red[512];
  __shared__ float red2[256];
  __shared__ float pc[10];
  {
    float gsum = 0.f;
#pragma unroll
    for (int tile = 0; tile < 16; tile++)
      gsum += gpart[(((size_t)b * 16 + tile) << 8) + t];
    in_s[t] = gsum * (1.0f / 4096.0f);
  }
  if (t < 64) in_s[256 + t] = a[b * 64 + t];
  __syncthreads();
  // h = relu([g,a] @ W_pre + b_pre)
  float acc = b_pre[t];
  for (int k = 0; k < 320; k++) acc = fmaf(in_s[k], W_pre[k * 256 + t], acc);
  float h = fmaxf(acc, 0.f);
  h_s[t] = h;
  h_t_out[t * 32 + b] = h;   // transposed [k][b] for k_cm staging
  __syncthreads();
  // fourier partials: all 256 threads (64 u-values x 4 k-groups)
  {
    int ui = t & 63, kg = t >> 6, j = ui & 31;
    const float* Wp = (ui < 32) ? W_pc : W_ps;
    float u = 0.f;
    int k0 = kg << 6;
    for (int k = k0; k < k0 + 64; k++) u = fmaf(h_s[k], Wp[k * 64 + j], u);
    red2[(ui << 2) | kg] = u;
  }
  __syncthreads();
  if (t < 64) {
    int j = t & 31;
    const float* bp = (t < 32) ? b_pc : b_ps;
    float u = bp[j] + (red2[t * 4] + red2[t * 4 + 1]) + (red2[t * 4 + 2] + red2[t * 4 + 3]);
    float wj = 1.0f + (float)j * (3.14159265358979323846f - 1.0f) / 31.0f;
    float su = sinf(u * wj), cu = cosf(u * wj);
    float* ph = (t < 32) ? phic_s : phis_s;
    ph[j] = su;
    ph[32 + j] = cu;
  }
  __syncthreads();   // guards phis_s reads AND red2 reuse below
  if (t < 64) phic_out[b * 64 + t] = phic_s[t];
  // m_base_c
  float mb = b_bc[t];
  for (int k = 0; k < 256; k++) mb = fmaf(h_s[k], W_bc[k * 256 + t], mb);
  mbc_out[b * 256 + t] = mb;
  // s-branch: Ws[b,s,r]*phi_s[r]
#pragma unroll
  for (int i = 0; i < 2; i++) {
    int idx = t + 256 * i;
    int s = idx >> 6, r = idx & 63;
    float v = b_Ws[s * 64 + r];
    for (int k = 0; k < 256; k++) v = fmaf(h_s[k], W_Ws[k * 512 + s * 64 + r], v);
    red[idx] = v * phis_s[r];
  }
  // m_base_s partials: (s, k-group of 8) over all 256 threads
  {
    int s = t & 7, kg = t >> 3;
    float v = 0.f;
    int k0 = kg << 3;
#pragma unroll
    for (int k = k0; k < k0 + 8; k++) v = fmaf(h_s[k], W_bs[k * 8 + s], v);
    red2[t] = v;
  }
  __syncthreads();
  if (t < 8) {
    float mbs = b_bs[t];
#pragma unroll
    for (int kg = 0; kg < 32; kg++) mbs += red2[kg * 8 + t];
    float sum = 0.f;
    for (int r = 0; r < 64; r++) sum += red[t * 64 + r];
    pc[t] = mbs * sum;
  }
  __syncthreads();
  if (t == 0) {
    pc[8] = -(pc[0] + pc[1] + pc[2] + pc[3]);
    pc[9] = -(pc[4] + pc[5] + pc[6] + pc[7]);
  }
  __syncthreads();
  // sigs stencil (y is L2-resident, 32 KB per b)
  const float* yb = y + (size_t)b * 2 * HWN;
  for (int px = t; px < 4096; px += 256) {
    int i = px >> 6, j = px & 63;
    float conv = 0.f;
#pragma unroll
    for (int k = 0; k < 2; k++) {
      const float* yk = yb + k * 4096;
      float up = (i > 0)  ? yk[px - 64] : 0.f;
      float dn = (i < 63) ? yk[px + 64] : 0.f;
      float lf = (j > 0)  ? yk[px - 1]  : 0.f;
      float rt = (j < 63) ? yk[px + 1]  : 0.f;
      conv += pc[k * 4 + 0] * up + pc[k * 4 + 1] * dn + pc[k * 4 + 2] * lf +
              pc[k * 4 + 3] * rt + pc[8 + k] * yk[px];
    }
    sigs[b * 4096 + px] = 1.f / (1.f + expf(-conv));
  }
}

// K3: sigc only — one block per channel, register-blocked (32 FMA per 3 LDS reads)
__global__ __launch_bounds__(512) void k_cm(
    const float* __restrict__ W_Wc, const float* __restrict__ b_Wc,
    const float* __restrict__ h_t, const float* __restrict__ phic_ws,
    const float* __restrict__ mbc_ws, float* __restrict__ sigc_out) {
  __shared__ __align__(16) float wsl[16384];   // [k=256][r=64]  64 KB
  __shared__ __align__(16) float h_s[8192];    // [k=256][b=32]  32 KB
  __shared__ __align__(16) float phi_s[2048];  // [b=32][r=64]    8 KB
  __shared__ float red[4096];                  // [kg=8][b=32][rq=16] 16 KB
  __shared__ float red2[512];                  // 2 KB  -> 124.9 KB, 1 block/CU
  int t = threadIdx.x, c = blockIdx.x;
  {
    const float4* col4 = (const float4*)(W_Wc + (size_t)c * 64);
    float4* wsl4 = (float4*)wsl;
#pragma unroll
    for (int i4 = t; i4 < 4096; i4 += 512) {
      int k = i4 >> 4, rq = i4 & 15;
      wsl4[i4] = col4[(size_t)k * 4096 + rq];
    }
    const float4* ht4 = (const float4*)h_t;
    float4* hs4 = (float4*)h_s;
#pragma unroll
    for (int i4 = t; i4 < 2048; i4 += 512) hs4[i4] = ht4[i4];
    ((float4*)phi_s)[t] = ((const float4*)phic_ws)[t];  // 512 float4 = 2048 floats
  }
  __syncthreads();
  int rq = t & 15, b8 = (t >> 4) & 3, kg = t >> 6;  // wave-uniform kg
  const float4* wv = (const float4*)wsl;
  float4 acc[8];
#pragma unroll
  for (int i = 0; i < 8; i++) acc[i] = {0.f, 0.f, 0.f, 0.f};
#pragma unroll 4
  for (int kk = 0; kk < 32; kk++) {
    int k = (kg << 5) + kk;
    float4 w4 = wv[k * 16 + rq];                       // 2-way broadcast: free
    const float4* hp = (const float4*)(h_s + k * 32 + (b8 << 3));
    float4 h0 = hp[0], h1 = hp[1];                     // broadcast: free
    float hv[8] = {h0.x, h0.y, h0.z, h0.w, h1.x, h1.y, h1.z, h1.w};
#pragma unroll
    for (int i = 0; i < 8; i++) {
      acc[i].x = fmaf(hv[i], w4.x, acc[i].x);
      acc[i].y = fmaf(hv[i], w4.y, acc[i].y);
      acc[i].z = fmaf(hv[i], w4.z, acc[i].z);
      acc[i].w = fmaf(hv[i], w4.w, acc[i].w);
    }
  }
  // bias added exactly once (kg==0), then dot with phi
  float4 bw = {0.f, 0.f, 0.f, 0.f};
  if (kg == 0) bw = ((const float4*)(b_Wc + (size_t)c * 64))[rq];
#pragma unroll
  for (int i = 0; i < 8; i++) {
    int bb = (b8 << 3) + i;
    float4 ph = ((const float4*)phi_s)[bb * 16 + rq];
    float4 av = acc[i];
    av.x += bw.x; av.y += bw.y; av.z += bw.z; av.w += bw.w;
    red[(kg * 32 + bb) * 16 + rq] =
        (av.x * ph.x + av.y * ph.y) + (av.z * ph.z + av.w * ph.w);
  }
  __syncthreads();
  {
    int bb = t >> 4, rr = t & 15;
    float tot = 0.f;
#pragma unroll
    for (int g = 0; g < 8; g++) tot += red[(g * 32 + bb) * 16 + rr];  // consecutive: free
    red2[t] = tot;
  }
  __syncthreads();
  if (t < 32) {
    float sum = 0.f;
#pragma unroll
    for (int i = 0; i < 16; i++) sum += red2[t * 16 + i];
    float v = mbc_ws[t * 256 + c] * sum;
    sigc_out[t * 256 + c] = 1.f / (1.f + expf(-v));
  }
}

// K4: out = x * (1 + sig_c[b,c] + sig_s[b,px])
__global__ __launch_bounds__(256) void k_final(const float* __restrict__ x,
                                               const float* __restrict__ sigc,
                                               const float* __restrict__ sigs,
                                               float* __restrict__ out) {
  size_t idx4 = (size_t)blockIdx.x * 256 + threadIdx.x;
  size_t flat = idx4 * 4;
  int b = (int)(flat >> 20);
  int c = (int)((flat >> 12) & 255);
  int px = (int)(flat & 4095);
  float4 xv = ((const float4*)x)[idx4];
  float sc = 1.0f + sigc[b * 256 + c];
  float4 ss = ((const float4*)sigs)[((size_t)b * HWN + px) >> 2];
  float4 o;
  o.x = xv.x * (sc + ss.x);
  o.y = xv.y * (sc + ss.y);
  o.z = xv.z * (sc + ss.z);
  o.w = xv.w * (sc + ss.w);
  ((float4*)out)[idx4] = o;
}

extern "C" void kernel_launch(void* const* d_in, const int* in_sizes, int n_in,
                              void* d_out, int out_size, void* d_ws, size_t ws_size,
                              hipStream_t stream) {
  const float* x     = (const float*)d_in[0];
  const float* a     = (const float*)d_in[1];
  const float* W_pre = (const float*)d_in[2];
  const float* b_pre = (const float*)d_in[3];
  const float* W_bc  = (const float*)d_in[4];
  const float* b_bc  = (const float*)d_in[5];
  const float* W_bs  = (const float*)d_in[6];
  const float* b_bs  = (const float*)d_in[7];
  const float* W_pc  = (const float*)d_in[8];
  const float* b_pc  = (const float*)d_in[9];
  const float* W_ps  = (const float*)d_in[10];
  const float* b_ps  = (const float*)d_in[11];
  const float* W_Wc  = (const float*)d_in[12];
  const float* b_Wc  = (const float*)d_in[13];
  const float* W_Ws  = (const float*)d_in[14];
  const float* b_Ws  = (const float*)d_in[15];
  float* out = (float*)d_out;
  float* ws  = (float*)d_ws;

  float* gpart_ws = ws + WS_GPART;
  float* ht_ws    = ws + WS_HT;
  float* phic_ws  = ws + WS_PHIC;
  float* mbc_ws   = ws + WS_MBC;
  float* sigc_ws  = ws + WS_SIGC;
  float* y_ws     = ws + WS_Y;
  float* sigs_ws  = ws + WS_SIGS;

  k_stats<<<dim3(16, BN), 256, 0, stream>>>(x, gpart_ws, y_ws);
  k_head<<<BN, 256, 0, stream>>>(gpart_ws, a, W_pre, b_pre, W_bc, b_bc, W_bs, b_bs,
                                 W_pc, b_pc, W_ps, b_ps, W_Ws, b_Ws, y_ws,
                                 ht_ws, phic_ws, mbc_ws, sigs_ws);
  k_cm<<<CN, 512, 0, stream>>>(W_Wc, b_Wc, ht_ws, phic_ws, mbc_ws, sigc_ws);
  k_final<<<(BN * CN * HWN) / 4 / 256, 256, 0, stream>>>(x, sigc_ws, sigs_ws, out);
}